// Round 6
// baseline (648.818 us; speedup 1.0000x reference)
//
#include <hip/hip_runtime.h>
#include <hip/hip_bf16.h>

#define NPATHS 100000
#define NLINKS 10000
#define TITERS 4
#define GRP    695              // 16-path groups per length class (695*16 >= 11112)
#define EDGES  799996           // sum of path lengths (4..12, mean 8)

typedef __hip_bfloat16 bf16;
typedef unsigned short u16;
typedef unsigned int   u32;
typedef _Float16 half8 __attribute__((ext_vector_type(8)));  // 8 fp16 MFMA frag
typedef __attribute__((ext_vector_type(4))) float float4v;   // MFMA acc

// ---- workspace layout ------------------------------------------------------
// u16 offsets (fp16 tables)
#define U_LNK 64            // link_state fp16 [10000*32]
#define U_KPB 320064        // K_path B-frags  [6][64][8]
#define U_RPB 323136        // R_path B-frags
#define U_KLB 326208        // K_link B-frags
#define U_RLB 329280        // R_link B-frags
#define U_W1T 332352        // W1 B-frags [16][64][8]
#define U_W2T 340544        // W2 B-frags [kb*16+t][64][8]  (ends 406080)
// float offsets (fp32 tables; 406080 u16 = 203040 f)
#define F_BP  203040
#define F_BL  203232
#define F_B1  203424
#define F_B2  203680
#define F_WF  203936        // 578 used
#define F_MAC 204544        // m_acc fp32 [10000*32]  (ends 524544)
#define U_WFP 1049088       // Wf ps-part B-frags [64][8] (u16; = float 524544..524800)
#define F_PS  524800        // ps (fp16, 100000*32) when ws is big enough
// byte offsets for the CSR / sorted-message fast path (after ps: 2099200+6400000)
#define B_CNT   8499200ULL                    // u32 counts[10000]
#define B_OFFE  8539200ULL                    // u32 offe[10001]
#define B_LP    8579208ULL                    // int2 lp[EDGES] = {link, pos}
#define B_MEDGE 14979200ULL                   // u16 medge[EDGES*32]
#define WS_NEED 66178944ULL                   // B_MEDGE + EDGES*64

__device__ __forceinline__ float bf2f(bf16 v) { return __bfloat162float(v); }
__device__ __forceinline__ u16 f2h_u(float f) {
    _Float16 h = (_Float16)f; u16 u; __builtin_memcpy(&u, &h, 2); return u;
}
__device__ __forceinline__ float h2f_u(u16 u) {
    _Float16 h; __builtin_memcpy(&h, &u, 2); return (float)h;
}
__device__ __forceinline__ float loadf(const void* p, int i, int isbf) {
    return isbf ? bf2f(((const bf16*)p)[i]) : ((const float*)p)[i];
}
__device__ __forceinline__ float sigmoid_(float v) { return 1.f / (1.f + __expf(-v)); }
__device__ __forceinline__ float tanh_(float v) { return 1.f - 2.f / (__expf(2.f * v) + 1.f); }
__device__ __forceinline__ float selu_(float v) {
    return v > 0.f ? 1.0507009873554805f * v : 1.7580993408473766f * (__expf(v) - 1.f);
}
__device__ __forceinline__ u16* ps_row(u16* ps0, u16* ps1, u16* ps2, int p) {
    return p < 49999 ? ps0 + (size_t)p * 32
         : (p < 99998 ? ps1 + (size_t)(p - 49999) * 32
                      : ps2 + (size_t)(p - 99998) * 32);
}

// ---- dtype probe (bf16 vs fp32 inputs) -----------------------------------
__global__ void probe_kernel(const u32* __restrict__ cap, int* __restrict__ flag) {
    if (threadIdx.x == 0 && blockIdx.x == 0) {
        bool ok = true;
        for (int i = 0; i < 8; ++i) {
            u32 w = cap[i];
            u32 e1 = (w >> 7) & 0xFF, e2 = (w >> 23) & 0xFF;
            ok = ok && e1 >= 122 && e1 <= 133 && e2 >= 122 && e2 <= 133;
        }
        *flag = ok ? 1 : 0;
    }
}

__global__ __launch_bounds__(256) void init_kernel(
    const void* __restrict__ traf, const void* __restrict__ cap, const int* __restrict__ flag,
    float* __restrict__ wsf, u16* __restrict__ wsu, u16* ps0, u16* ps1, u16* ps2,
    const void* Kp, const void* Rp, const void* bp,
    const void* Kl, const void* Rl, const void* bl,
    const void* W1, const void* b1, const void* W2, const void* b2,
    const void* Wf, const void* bfv)
{
    const int isbf = *flag;
    const int i = blockIdx.x * 256 + threadIdx.x;
    if (i < NPATHS) {
        u32 ww[16];
        ww[0] = (u32)f2h_u(loadf(traf, i, isbf));
#pragma unroll
        for (int k = 1; k < 16; ++k) ww[k] = 0;
        uint4* row = (uint4*)ps_row(ps0, ps1, ps2, i);
        row[0] = *(uint4*)(ww + 0);  row[1] = *(uint4*)(ww + 4);
        row[2] = *(uint4*)(ww + 8);  row[3] = *(uint4*)(ww + 12);
    }
    int j;
    j = i;          if (j >= 0 && j < 320000)       // link_state fp16
        wsu[U_LNK + j] = ((j & 31) == 0) ? f2h_u(loadf(cap, j >> 5, isbf)) : (u16)0;
    j = i - 320000; if (j >= 0 && j < 3072) {       // K_path B-frags [t][lane][8]
        int t = j >> 9, lane = (j >> 3) & 63, e = j & 7;
        int k = (lane >> 4) * 8 + e, n = t * 16 + (lane & 15);
        wsu[U_KPB + j] = f2h_u(loadf(Kp, k * 96 + n, isbf));
    }
    j = i - 323072; if (j >= 0 && j < 3072) {       // R_path B-frags
        int t = j >> 9, lane = (j >> 3) & 63, e = j & 7;
        int k = (lane >> 4) * 8 + e, n = t * 16 + (lane & 15);
        wsu[U_RPB + j] = f2h_u(loadf(Rp, k * 96 + n, isbf));
    }
    j = i - 326144; if (j >= 0 && j < 3072) {       // K_link B-frags
        int t = j >> 9, lane = (j >> 3) & 63, e = j & 7;
        int k = (lane >> 4) * 8 + e, n = t * 16 + (lane & 15);
        wsu[U_KLB + j] = f2h_u(loadf(Kl, k * 96 + n, isbf));
    }
    j = i - 329216; if (j >= 0 && j < 3072) {       // R_link B-frags
        int t = j >> 9, lane = (j >> 3) & 63, e = j & 7;
        int k = (lane >> 4) * 8 + e, n = t * 16 + (lane & 15);
        wsu[U_RLB + j] = f2h_u(loadf(Rl, k * 96 + n, isbf));
    }
    j = i - 332288; if (j >= 0 && j < 192)   wsf[F_BP + j] = loadf(bp, j, isbf);
    j = i - 332480; if (j >= 0 && j < 192)   wsf[F_BL + j] = loadf(bl, j, isbf);
    j = i - 332672; if (j >= 0 && j < 256)   wsf[F_B1 + j] = loadf(b1, j, isbf);
    j = i - 332928; if (j >= 0 && j < 256)   wsf[F_B2 + j] = loadf(b2, j, isbf);
    j = i - 333184; if (j >= 0 && j < 578)
        wsf[F_WF + j] = (j < 576) ? loadf(Wf, j, isbf) : loadf(bfv, j - 576, isbf);
    j = i - 334000; if (j >= 0 && j < 8192) {       // W1 B-frags [t][lane][8]
        int t = j >> 9, lane = (j >> 3) & 63, e = j & 7;
        int k = (lane >> 4) * 8 + e, n = t * 16 + (lane & 15);
        wsu[U_W1T + j] = f2h_u(loadf(W1, k * 256 + n, isbf));
    }
    j = i - 343000; if (j >= 0 && j < 65536) {      // W2 B-frags, kb-major: [kb*16+t][lane][8]
        int g = j >> 9, kb = g >> 4, t = g & 15;
        int lane = (j >> 3) & 63, e = j & 7;
        int k = kb * 32 + (lane >> 4) * 8 + e, n = t * 16 + (lane & 15);
        wsu[U_W2T + j] = f2h_u(loadf(W2, k * 256 + n, isbf));
    }
    j = i - 408576; if (j >= 0 && j < 512) {        // Wf ps-part B-frags [lane][8] (n<2 real)
        int lane = j >> 3, e = j & 7;
        int k = (lane >> 4) * 8 + e, n = lane & 15;
        wsu[U_WFP + j] = (n < 2) ? f2h_u(loadf(Wf, (256 + k) * 2 + n, isbf)) : (u16)0;
    }
}

// ---- CSR build (once per launch; links topology is static) -----------------
__global__ __launch_bounds__(256) void hist_kernel(const int* __restrict__ links,
                                                   u32* __restrict__ cnt) {
    const int e = blockIdx.x * 256 + threadIdx.x;
    if (e < EDGES) atomicAdd(&cnt[links[e]], 1u);
}

__global__ __launch_bounds__(256) void scan_kernel(const u32* __restrict__ cnt,
                                                   u32* __restrict__ offe) {
    __shared__ u32 part[257];
    const int t = threadIdx.x;
    u32 s = 0;
#pragma unroll 1
    for (int i = 0; i < 40; ++i) { int b = t * 40 + i; if (b < NLINKS) s += cnt[b]; }
    part[t + 1] = s;
    if (t == 0) part[0] = 0;
    __syncthreads();
    if (t == 0) {
        u32 r = 0;
        for (int i = 1; i <= 256; ++i) { r += part[i]; part[i] = r; }
    }
    __syncthreads();
    u32 run = part[t];                        // exclusive prefix of this chunk
#pragma unroll 1
    for (int i = 0; i < 40; ++i) {
        int b = t * 40 + i;
        if (b < NLINKS) { offe[b] = run; run += cnt[b]; }
    }
    if (t == 255) offe[NLINKS] = run;
}

// assigns each edge a slot within its link's CSR range; converts offe[l] into
// the INCLUSIVE end of link l's range (= original offe[l+1]).
__global__ __launch_bounds__(256) void pos_kernel(const int* __restrict__ links,
                                                  u32* __restrict__ offe,
                                                  int2* __restrict__ lp) {
    const int e = blockIdx.x * 256 + threadIdx.x;
    if (e < EDGES) {
        const int l = links[e];
        const u32 p = atomicAdd(&offe[l], 1u);
        lp[e] = make_int2(l, (int)p);
    }
}

// ---- segment-sum over sorted messages: 1 wave/link, uint4-coalesced --------
// OVERWRITES m_acc (no memset needed). 16 edges x 64 B contiguous per pass.
__global__ __launch_bounds__(256) void gather_m(const u16* __restrict__ medge,
                                                const u32* __restrict__ offe,
                                                float* __restrict__ m_acc) {
    const int tid = threadIdx.x;
    const int l = blockIdx.x * 4 + (tid >> 6);
    if (l >= NLINKS) return;
    const int lane = tid & 63;
    const int dp = lane & 3, eg = lane >> 2;      // 4 dim-chunks x 16 edge slots
    const u32 s1 = offe[l];                       // inclusive end (post pos_kernel)
    const u32 s0 = (l == 0) ? 0u : offe[l - 1];
    float a[8] = {0.f, 0.f, 0.f, 0.f, 0.f, 0.f, 0.f, 0.f};
    for (u32 e = s0 + eg; e < s1; e += 16) {
        const uint4 v = *(const uint4*)(medge + (size_t)e * 32 + dp * 8);
        const u32 w[4] = {v.x, v.y, v.z, v.w};
#pragma unroll
        for (int k = 0; k < 4; ++k) {
            a[2 * k]     += h2f_u((u16)(w[k] & 0xFFFF));
            a[2 * k + 1] += h2f_u((u16)(w[k] >> 16));
        }
    }
#pragma unroll
    for (int msk = 4; msk < 64; msk <<= 1)
#pragma unroll
        for (int k = 0; k < 8; ++k) a[k] += __shfl_xor(a[k], msk);
    if (eg == 0) {
        float4 o0 = make_float4(a[0], a[1], a[2], a[3]);
        float4 o1 = make_float4(a[4], a[5], a[6], a[7]);
        *(float4*)(m_acc + (size_t)l * 32 + dp * 8)     = o0;
        *(float4*)(m_acc + (size_t)l * 32 + dp * 8 + 4) = o1;
    }
}

// ---- fp16 MFMA path GRU: 16 paths/wave, 12 mfma/step, x prefetched --------
// Class-interleaved grid (c = bid%9): all 9 length classes in flight (r2->r4).
// min-waves stays 3 (6 forced a 40-VGPR spill, 2.2x slower -- r3).
// SORTED=1: plain fp16 stores to pre-assigned CSR slots (no atomic RMW);
// SORTED=0: legacy fp32 atomic scatter (needs m_acc pre-zeroed).
template<int SORTED>
__global__ __launch_bounds__(256, 3) void path_gru_mfma(
    const int* __restrict__ links, const int2* __restrict__ lp,
    const u16* __restrict__ KPB, const u16* __restrict__ RPB,
    const float* __restrict__ bp,
    const u16* __restrict__ lnk16,
    u16* ps0, u16* ps1, u16* ps2, float* __restrict__ m_acc,
    u16* __restrict__ medge)
{
    __shared__ u16 hlds[4][16 * 40];      // 40-u16 row stride: aligned + 2-way only
    const int tid = threadIdx.x;
    const int wv = tid >> 6, lane = tid & 63;
    const int q = lane >> 4, col = lane & 15;
    const int c = blockIdx.x % 9;                 // class-interleaved grid
    const int gi = (blockIdx.x / 9) * 4 + wv;
    if (gi >= GRP) return;
    const int cnt = (c == 0) ? 11112 : 11111;
    const int idx0 = gi * 16;
    const int L = 4 + c;

    const int idxc = idx0 + col;
    const int actc = idxc < cnt;
    const int idcl = min(idxc, cnt - 1);
    const int pc   = c + 9 * idcl;
    const int offc = 4 * pc + idcl * 36 + (c * (c - 1)) / 2;

    u16* hw = hlds[wv];

    half8 KB[6], RB[6];
#pragma unroll
    for (int t = 0; t < 6; ++t) {
        KB[t] = *(const half8*)(KPB + t * 512 + lane * 8);
        RB[t] = *(const half8*)(RPB + t * 512 + lane * 8);
    }
    float xzb[6], hzb[6];
#pragma unroll
    for (int t = 0; t < 6; ++t) { xzb[t] = bp[t * 16 + col]; hzb[t] = bp[96 + t * 16 + col]; }

    half8 Ah = *(const half8*)(ps_row(ps0, ps1, ps2, pc) + q * 8);
    float hold[2][4];
#pragma unroll
    for (int t = 0; t < 2; ++t)
#pragma unroll
        for (int r = 0; r < 4; ++r) {
            int idr = min(idx0 + q * 4 + r, cnt - 1);
            int pr = c + 9 * idr;
            hold[t][r] = h2f_u(ps_row(ps0, ps1, ps2, pr)[t * 16 + col]);
        }

    int2 cur;
    if (SORTED) cur = actc ? lp[offc] : make_int2(-1, -1);
    else        cur = make_int2(actc ? links[offc] : -1, -1);
    half8 Ax = *(const half8*)(lnk16 + (size_t)max(cur.x, 0) * 32 + q * 8);

    for (int s = 0; s < L; ++s) {
        // prefetch next step's x while computing this step
        int2 nxt;
        if (SORTED) nxt = (s + 1 < L && actc) ? lp[offc + s + 1] : make_int2(-1, -1);
        else        nxt = make_int2((s + 1 < L && actc) ? links[offc + s + 1] : -1, -1);
        const half8 Ax_nxt = *(const half8*)(lnk16 + (size_t)max(nxt.x, 0) * 32 + q * 8);

        float4v xz[6], hz[6];
#pragma unroll
        for (int t = 0; t < 6; ++t) {
            float4v ix = {xzb[t], xzb[t], xzb[t], xzb[t]};
            float4v ih = {hzb[t], hzb[t], hzb[t], hzb[t]};
            xz[t] = __builtin_amdgcn_mfma_f32_16x16x32_f16(Ax, KB[t], ix, 0, 0, 0);
            hz[t] = __builtin_amdgcn_mfma_f32_16x16x32_f16(Ah, RB[t], ih, 0, 0, 0);
        }
#pragma unroll
        for (int t = 0; t < 2; ++t)
#pragma unroll
            for (int r = 0; r < 4; ++r) {
                const float z  = sigmoid_(xz[t][r] + hz[t][r]);
                const float rr = sigmoid_(xz[t + 2][r] + hz[t + 2][r]);
                const float hh = tanh_(xz[t + 4][r] + rr * hz[t + 4][r]);
                const float hn = z * hold[t][r] + (1.f - z) * hh;
                hold[t][r] = hn;
                hw[(q * 4 + r) * 40 + t * 16 + col] = f2h_u(hn);
            }
        // C -> A transpose via LDS
        Ah = *(const half8*)(hw + col * 40 + q * 8);
        if (SORTED) {
            // plain coalesced store: 4 edges x 64B per pass, CSR slot from lp.y
            const int dp = lane & 15, eg = lane >> 4;
#pragma unroll
            for (int j4 = 0; j4 < 4; ++j4) {
                const int src = 4 * j4 + eg;
                const int tp = __shfl(cur.y, src);
                const u32 v = *(const u32*)(hw + src * 40 + 2 * dp);
                if (tp >= 0) *(u32*)(medge + (size_t)tp * 32 + 2 * dp) = v;
            }
        } else {
            // legacy: coalesced atomic flush, 2 links x 32 dims per instr
            const int half_ = lane >> 5, kk = lane & 31;
#pragma unroll
            for (int j2 = 0; j2 < 8; ++j2) {
                const int src = 2 * j2 + half_;
                const int tgt = __shfl(cur.x, src);
                const float v = h2f_u(hw[src * 40 + kk]);
                if (tgt >= 0) unsafeAtomicAdd(m_acc + (size_t)tgt * 32 + kk, v);
            }
        }
        cur = nxt; Ax = Ax_nxt;
    }
    if (actc) {
        uint4 tmp; __builtin_memcpy(&tmp, &Ah, 16);
        *(uint4*)(ps_row(ps0, ps1, ps2, pc) + q * 8) = tmp;
    }
}

// ---- fp16 MFMA link GRU: 16 links/wave, one step ---------------------------
__global__ __launch_bounds__(256) void link_gru_mfma(
    const u16* __restrict__ KLB, const u16* __restrict__ RLB,
    const float* __restrict__ bl,
    const float* __restrict__ m_in, u16* __restrict__ lnk16)
{
    __shared__ u16 hlds[4][16 * 40];
    const int tid = threadIdx.x;
    const int wv = tid >> 6, lane = tid & 63;
    const int q = lane >> 4, col = lane & 15;
    const int w = blockIdx.x * 4 + wv;
    if (w >= NLINKS / 16) return;
    const int base = w * 16;
    u16* hw = hlds[wv];

    half8 KB[6], RB[6];
#pragma unroll
    for (int t = 0; t < 6; ++t) {
        KB[t] = *(const half8*)(KLB + t * 512 + lane * 8);
        RB[t] = *(const half8*)(RLB + t * 512 + lane * 8);
    }
    float xzb[6], hzb[6];
#pragma unroll
    for (int t = 0; t < 6; ++t) { xzb[t] = bl[t * 16 + col]; hzb[t] = bl[96 + t * 16 + col]; }

    // x = m row (fp32) -> fp16 A-frag;  h = link row (fp16) A-frag + C-layout copy
    half8 Ax;
    {
        const float4* mr = (const float4*)(m_in + (size_t)(base + col) * 32 + q * 8);
        float4 a = mr[0], b = mr[1];
        _Float16 xv[8] = {(_Float16)a.x, (_Float16)a.y, (_Float16)a.z, (_Float16)a.w,
                          (_Float16)b.x, (_Float16)b.y, (_Float16)b.z, (_Float16)b.w};
        __builtin_memcpy(&Ax, xv, 16);
    }
    half8 Ah = *(const half8*)(lnk16 + (size_t)(base + col) * 32 + q * 8);
    float hold[2][4];
#pragma unroll
    for (int t = 0; t < 2; ++t)
#pragma unroll
        for (int r = 0; r < 4; ++r)
            hold[t][r] = h2f_u(lnk16[(size_t)(base + q * 4 + r) * 32 + t * 16 + col]);

    float4v xz[6], hz[6];
#pragma unroll
    for (int t = 0; t < 6; ++t) {
        float4v ix = {xzb[t], xzb[t], xzb[t], xzb[t]};
        float4v ih = {hzb[t], hzb[t], hzb[t], hzb[t]};
        xz[t] = __builtin_amdgcn_mfma_f32_16x16x32_f16(Ax, KB[t], ix, 0, 0, 0);
        hz[t] = __builtin_amdgcn_mfma_f32_16x16x32_f16(Ah, RB[t], ih, 0, 0, 0);
    }
#pragma unroll
    for (int t = 0; t < 2; ++t)
#pragma unroll
        for (int r = 0; r < 4; ++r) {
            const float z  = sigmoid_(xz[t][r] + hz[t][r]);
            const float rr = sigmoid_(xz[t + 2][r] + hz[t + 2][r]);
            const float hh = tanh_(xz[t + 4][r] + rr * hz[t + 4][r]);
            const float hn = z * hold[t][r] + (1.f - z) * hh;
            hw[(q * 4 + r) * 40 + t * 16 + col] = f2h_u(hn);
        }
    // transpose -> contiguous fp16 row store
    {
        uint4 tmp = *(const uint4*)(hw + col * 40 + q * 8);
        *(uint4*)(lnk16 + (size_t)(base + col) * 32 + q * 8) = tmp;
    }
}

// ---- fp16 MFMA readout: r0 streaming body (4 blocks/CU) + MFMA ps-tail -----
__global__ __launch_bounds__(256) void readout_mfma(
    u16* ps0, u16* ps1, u16* ps2,
    const u16* __restrict__ W1T, const u16* __restrict__ W2T,
    const u16* __restrict__ WFPT,
    const float* __restrict__ b1f, const float* __restrict__ b2f,
    const float* __restrict__ Wff,
    const int* __restrict__ flag, void* __restrict__ out)
{
    __shared__ u16  sA[4][4096];
    __shared__ float sB1[256], sB2[256], sWf[578];
    const int tid = threadIdx.x;
    if (tid < 256) { sB1[tid] = b1f[tid]; sB2[tid] = b2f[tid]; }
    for (int i = tid; i < 578; i += 256) sWf[i] = Wff[i];
    __syncthreads();

    const int w = tid >> 6, lane = tid & 63;
    const int col = lane & 15, q = lane >> 4;
    const int pbase = blockIdx.x * 64 + w * 16;
    u16* sAw = sA[w];

    const int pa = min(pbase + col, NPATHS - 1);
    const half8 aps = *(const half8*)(ps_row(ps0, ps1, ps2, pa) + q * 8);
    const half8 wfp = *(const half8*)(WFPT + lane * 8);

    // ---- W1 phase: h1 = selu(ps @ W1 + b1), stored to sA in A-layout ----
#pragma unroll
    for (int t = 0; t < 16; ++t) {
        const half8 bfrag = *(const half8*)(W1T + t * 512 + lane * 8);   // coalesced
        float4v acc = {0.f, 0.f, 0.f, 0.f};
        acc = __builtin_amdgcn_mfma_f32_16x16x32_f16(aps, bfrag, acc, 0, 0, 0);
        const int kb = t >> 1;
        const int qp = 2 * (t & 1) + (col >> 3);
#pragma unroll
        for (int rI = 0; rI < 4; ++rI) {
            const int m = q * 4 + rI;
            const float h1 = selu_(acc[rI] + sB1[t * 16 + col]);
            sAw[kb * 512 + qp * 128 + m * 8 + (col & 7)] = f2h_u(h1);
        }
    }
    half8 afr[8];
#pragma unroll
    for (int kb = 0; kb < 8; ++kb)
        afr[kb] = *(const half8*)(sAw + kb * 512 + lane * 8);

    // ---- W2 phase: stream kb-major B-frags from L2 ----
    float4v acc2[16];
#pragma unroll
    for (int t = 0; t < 16; ++t) acc2[t] = (float4v){0.f, 0.f, 0.f, 0.f};
#pragma unroll
    for (int kb = 0; kb < 8; ++kb) {
#pragma unroll
        for (int t = 0; t < 16; ++t) {
            const half8 bfrag = *(const half8*)(W2T + (kb * 16 + t) * 512 + lane * 8);
            acc2[t] = __builtin_amdgcn_mfma_f32_16x16x32_f16(afr[kb], bfrag, acc2[t], 0, 0, 0);
        }
    }

    // ---- readout tail: h2 = selu(.+b2); pred = h2@Wf2 + ps@Wfp + bf --------
    float p0[4] = {0.f, 0.f, 0.f, 0.f}, p1[4] = {0.f, 0.f, 0.f, 0.f};
#pragma unroll
    for (int t = 0; t < 16; ++t) {
        const int n = t * 16 + col;
        const float wf0 = sWf[2 * n], wf1 = sWf[2 * n + 1];
#pragma unroll
        for (int rI = 0; rI < 4; ++rI) {
            const float h2 = selu_(acc2[t][rI] + sB2[n]);
            p0[rI] += h2 * wf0; p1[rI] += h2 * wf1;
        }
    }
#pragma unroll
    for (int msk = 1; msk < 16; msk <<= 1) {
#pragma unroll
        for (int rI = 0; rI < 4; ++rI) {
            p0[rI] += __shfl_xor(p0[rI], msk);
            p1[rI] += __shfl_xor(p1[rI], msk);
        }
    }
    // ps @ Wfp via one MFMA on the already-loaded ps A-frag (cols 0/1 real)
    float4v accp = {0.f, 0.f, 0.f, 0.f};
    accp = __builtin_amdgcn_mfma_f32_16x16x32_f16(aps, wfp, accp, 0, 0, 0);
    float oc[4];
#pragma unroll
    for (int rI = 0; rI < 4; ++rI) oc[rI] = __shfl_xor(accp[rI], 1);
    if (col == 0) {
        const int isbf = *flag;
#pragma unroll
        for (int rI = 0; rI < 4; ++rI) {
            const int pp = pbase + q * 4 + rI;
            if (pp < NPATHS) {
                const float s0 = p0[rI] + accp[rI] + sWf[576];
                const float s1 = p1[rI] + oc[rI]   + sWf[577];
                if (isbf) {
                    __hip_bfloat162 o;
                    o.x = __float2bfloat16(s0);
                    o.y = __float2bfloat16(s1);
                    ((__hip_bfloat162*)out)[pp] = o;
                } else {
                    ((float2*)out)[pp] = make_float2(s0, s1);
                }
            }
        }
    }
}

extern "C" void kernel_launch(void* const* d_in, const int* in_sizes, int n_in,
                              void* d_out, int out_size, void* d_ws, size_t ws_size,
                              hipStream_t stream)
{
    const int* links = (const int*)d_in[2];
    float* wsf = (float*)d_ws;
    u16*   wsu = (u16*)d_ws;
    int*   flag = (int*)d_ws;
    char*  wsb = (char*)d_ws;

    u16* wps = (u16*)(wsf + F_PS);
    u16 *ps0, *ps1, *ps2;
    if (ws_size >= (size_t)F_PS * 4 + 6400000 + 256) {
        ps0 = wps; ps1 = wps + (size_t)49999 * 32; ps2 = wps + (size_t)99998 * 32;
    } else {
        ps0 = (u16*)d_in[3]; ps1 = (u16*)d_in[4]; ps2 = wps;  // 2 spill rows
    }

    const int big = ws_size >= (size_t)WS_NEED;
    u32*  cnt   = (u32*)(wsb + B_CNT);
    u32*  offe  = (u32*)(wsb + B_OFFE);
    int2* lp    = (int2*)(wsb + B_LP);
    u16*  medge = (u16*)(wsb + B_MEDGE);

    probe_kernel<<<1, 64, 0, stream>>>((const u32*)d_in[0], flag);
    init_kernel<<<1599, 256, 0, stream>>>(d_in[1], d_in[0], flag, wsf, wsu, ps0, ps1, ps2,
                                          d_in[10], d_in[11], d_in[12],
                                          d_in[7], d_in[8], d_in[9],
                                          d_in[13], d_in[14], d_in[15], d_in[16],
                                          d_in[17], d_in[18]);
    if (big) {
        hipMemsetAsync(cnt, 0, NLINKS * sizeof(u32), stream);
        hist_kernel<<<(EDGES + 255) / 256, 256, 0, stream>>>(links, cnt);
        scan_kernel<<<1, 256, 0, stream>>>(cnt, offe);
        pos_kernel<<<(EDGES + 255) / 256, 256, 0, stream>>>(links, offe, lp);
    }

    const int pg_blocks = 9 * ((GRP + 3) / 4);   // class-interleaved grid (1566)
    const int lg_blocks = (NLINKS / 16 + 3) / 4;
    for (int t = 0; t < TITERS; ++t) {
        if (big) {
            path_gru_mfma<1><<<pg_blocks, 256, 0, stream>>>(
                links, lp, wsu + U_KPB, wsu + U_RPB, wsf + F_BP,
                wsu + U_LNK, ps0, ps1, ps2, wsf + F_MAC, medge);
            gather_m<<<(NLINKS + 3) / 4, 256, 0, stream>>>(medge, offe, wsf + F_MAC);
        } else {
            hipMemsetAsync(wsf + F_MAC, 0, NLINKS * 32 * sizeof(float), stream);
            path_gru_mfma<0><<<pg_blocks, 256, 0, stream>>>(
                links, lp, wsu + U_KPB, wsu + U_RPB, wsf + F_BP,
                wsu + U_LNK, ps0, ps1, ps2, wsf + F_MAC, medge);
        }
        link_gru_mfma<<<lg_blocks, 256, 0, stream>>>(
            wsu + U_KLB, wsu + U_RLB, wsf + F_BL, wsf + F_MAC, wsu + U_LNK);
    }
    readout_mfma<<<(NPATHS + 63) / 64, 256, 0, stream>>>(
        ps0, ps1, ps2,
        wsu + U_W1T, wsu + U_W2T, wsu + U_WFP,
        wsf + F_B1, wsf + F_B2, wsf + F_WF, flag, d_out);
}

// Round 7
// 575.820 us; speedup vs baseline: 1.1268x; 1.1268x over previous
//
#include <hip/hip_runtime.h>
#include <hip/hip_bf16.h>

#define NPATHS 100000
#define NLINKS 10000
#define TITERS 4
#define GRP    695              // 16-path groups per length class (695*16 >= 11112)

typedef __hip_bfloat16 bf16;
typedef unsigned short u16;
typedef unsigned int   u32;
typedef _Float16 half8 __attribute__((ext_vector_type(8)));  // 8 fp16 MFMA frag
typedef __attribute__((ext_vector_type(4))) float float4v;   // MFMA acc

// ---- workspace layout ------------------------------------------------------
// u16 offsets (fp16 tables)
#define U_LNK 64            // link_state fp16 [10000*32]
#define U_KPB 320064        // K_path B-frags  [6][64][8]
#define U_RPB 323136        // R_path B-frags
#define U_KLB 326208        // K_link B-frags
#define U_RLB 329280        // R_link B-frags
#define U_W1T 332352        // W1 B-frags [16][64][8]
#define U_W2T 340544        // W2 B-frags [kb*16+t][64][8]  (ends 406080)
// float offsets (fp32 tables; 406080 u16 = 203040 f)
#define F_BP  203040
#define F_BL  203232
#define F_B1  203424
#define F_B2  203680
#define F_WF  203936        // 578 used
#define F_MAC 204544        // m_acc fp32 [10000*32]  (ends 524544)
#define U_WFP 1049088       // Wf ps-part B-frags [64][8] (u16; = float 524544..524800)
#define F_PS  524800        // ps (fp16, 100000*32) when ws is big enough

__device__ __forceinline__ float bf2f(bf16 v) { return __bfloat162float(v); }
__device__ __forceinline__ u16 f2h_u(float f) {
    _Float16 h = (_Float16)f; u16 u; __builtin_memcpy(&u, &h, 2); return u;
}
__device__ __forceinline__ float h2f_u(u16 u) {
    _Float16 h; __builtin_memcpy(&h, &u, 2); return (float)h;
}
__device__ __forceinline__ float loadf(const void* p, int i, int isbf) {
    return isbf ? bf2f(((const bf16*)p)[i]) : ((const float*)p)[i];
}
__device__ __forceinline__ float sigmoid_(float v) { return 1.f / (1.f + __expf(-v)); }
__device__ __forceinline__ float tanh_(float v) { return 1.f - 2.f / (__expf(2.f * v) + 1.f); }
__device__ __forceinline__ float selu_(float v) {
    return v > 0.f ? 1.0507009873554805f * v : 1.7580993408473766f * (__expf(v) - 1.f);
}
__device__ __forceinline__ u16* ps_row(u16* ps0, u16* ps1, u16* ps2, int p) {
    return p < 49999 ? ps0 + (size_t)p * 32
         : (p < 99998 ? ps1 + (size_t)(p - 49999) * 32
                      : ps2 + (size_t)(p - 99998) * 32);
}

// ---- dtype probe (bf16 vs fp32 inputs) -----------------------------------
__global__ void probe_kernel(const u32* __restrict__ cap, int* __restrict__ flag) {
    if (threadIdx.x == 0 && blockIdx.x == 0) {
        bool ok = true;
        for (int i = 0; i < 8; ++i) {
            u32 w = cap[i];
            u32 e1 = (w >> 7) & 0xFF, e2 = (w >> 23) & 0xFF;
            ok = ok && e1 >= 122 && e1 <= 133 && e2 >= 122 && e2 <= 133;
        }
        *flag = ok ? 1 : 0;
    }
}

__global__ __launch_bounds__(256) void init_kernel(
    const void* __restrict__ traf, const void* __restrict__ cap, const int* __restrict__ flag,
    float* __restrict__ wsf, u16* __restrict__ wsu, u16* ps0, u16* ps1, u16* ps2,
    const void* Kp, const void* Rp, const void* bp,
    const void* Kl, const void* Rl, const void* bl,
    const void* W1, const void* b1, const void* W2, const void* b2,
    const void* Wf, const void* bfv)
{
    const int isbf = *flag;
    const int i = blockIdx.x * 256 + threadIdx.x;
    if (i < NPATHS) {
        u32 ww[16];
        ww[0] = (u32)f2h_u(loadf(traf, i, isbf));
#pragma unroll
        for (int k = 1; k < 16; ++k) ww[k] = 0;
        uint4* row = (uint4*)ps_row(ps0, ps1, ps2, i);
        row[0] = *(uint4*)(ww + 0);  row[1] = *(uint4*)(ww + 4);
        row[2] = *(uint4*)(ww + 8);  row[3] = *(uint4*)(ww + 12);
    }
    int j;
    j = i;          if (j >= 0 && j < 320000)       // link_state fp16
        wsu[U_LNK + j] = ((j & 31) == 0) ? f2h_u(loadf(cap, j >> 5, isbf)) : (u16)0;
    j = i - 320000; if (j >= 0 && j < 3072) {       // K_path B-frags [t][lane][8]
        int t = j >> 9, lane = (j >> 3) & 63, e = j & 7;
        int k = (lane >> 4) * 8 + e, n = t * 16 + (lane & 15);
        wsu[U_KPB + j] = f2h_u(loadf(Kp, k * 96 + n, isbf));
    }
    j = i - 323072; if (j >= 0 && j < 3072) {       // R_path B-frags
        int t = j >> 9, lane = (j >> 3) & 63, e = j & 7;
        int k = (lane >> 4) * 8 + e, n = t * 16 + (lane & 15);
        wsu[U_RPB + j] = f2h_u(loadf(Rp, k * 96 + n, isbf));
    }
    j = i - 326144; if (j >= 0 && j < 3072) {       // K_link B-frags
        int t = j >> 9, lane = (j >> 3) & 63, e = j & 7;
        int k = (lane >> 4) * 8 + e, n = t * 16 + (lane & 15);
        wsu[U_KLB + j] = f2h_u(loadf(Kl, k * 96 + n, isbf));
    }
    j = i - 329216; if (j >= 0 && j < 3072) {       // R_link B-frags
        int t = j >> 9, lane = (j >> 3) & 63, e = j & 7;
        int k = (lane >> 4) * 8 + e, n = t * 16 + (lane & 15);
        wsu[U_RLB + j] = f2h_u(loadf(Rl, k * 96 + n, isbf));
    }
    j = i - 332288; if (j >= 0 && j < 192)   wsf[F_BP + j] = loadf(bp, j, isbf);
    j = i - 332480; if (j >= 0 && j < 192)   wsf[F_BL + j] = loadf(bl, j, isbf);
    j = i - 332672; if (j >= 0 && j < 256)   wsf[F_B1 + j] = loadf(b1, j, isbf);
    j = i - 332928; if (j >= 0 && j < 256)   wsf[F_B2 + j] = loadf(b2, j, isbf);
    j = i - 333184; if (j >= 0 && j < 578)
        wsf[F_WF + j] = (j < 576) ? loadf(Wf, j, isbf) : loadf(bfv, j - 576, isbf);
    j = i - 334000; if (j >= 0 && j < 8192) {       // W1 B-frags [t][lane][8]
        int t = j >> 9, lane = (j >> 3) & 63, e = j & 7;
        int k = (lane >> 4) * 8 + e, n = t * 16 + (lane & 15);
        wsu[U_W1T + j] = f2h_u(loadf(W1, k * 256 + n, isbf));
    }
    j = i - 343000; if (j >= 0 && j < 65536) {      // W2 B-frags, kb-major: [kb*16+t][lane][8]
        int g = j >> 9, kb = g >> 4, t = g & 15;
        int lane = (j >> 3) & 63, e = j & 7;
        int k = kb * 32 + (lane >> 4) * 8 + e, n = t * 16 + (lane & 15);
        wsu[U_W2T + j] = f2h_u(loadf(W2, k * 256 + n, isbf));
    }
    j = i - 408576; if (j >= 0 && j < 512) {        // Wf ps-part B-frags [lane][8] (n<2 real)
        int lane = j >> 3, e = j & 7;
        int k = (lane >> 4) * 8 + e, n = lane & 15;
        wsu[U_WFP + j] = (n < 2) ? f2h_u(loadf(Wf, (256 + k) * 2 + n, isbf)) : (u16)0;
    }
}

// ---- fp16 MFMA path GRU: 16 paths/wave, 12 mfma/step, x prefetched --------
// Class-interleaved grid (c = bid%9): all 9 length classes in flight (r2->r4).
// min-waves stays 3 (6 forced a 40-VGPR spill, 2.2x slower -- r3).
// Atomic flush kept: r1/r6 proved sorted-store+gather is net SLOWER (+58 us).
__global__ __launch_bounds__(256, 3) void path_gru_mfma(
    const int* __restrict__ links,
    const u16* __restrict__ KPB, const u16* __restrict__ RPB,
    const float* __restrict__ bp,
    const u16* __restrict__ lnk16,
    u16* ps0, u16* ps1, u16* ps2, float* __restrict__ m_acc)
{
    __shared__ u16 hlds[4][16 * 40];      // 40-u16 row stride: aligned + 2-way only
    const int tid = threadIdx.x;
    const int wv = tid >> 6, lane = tid & 63;
    const int q = lane >> 4, col = lane & 15;
    const int c = blockIdx.x % 9;                 // class-interleaved grid
    const int gi = (blockIdx.x / 9) * 4 + wv;
    if (gi >= GRP) return;
    const int cnt = (c == 0) ? 11112 : 11111;
    const int idx0 = gi * 16;
    const int L = 4 + c;

    const int idxc = idx0 + col;
    const int actc = idxc < cnt;
    const int idcl = min(idxc, cnt - 1);
    const int pc   = c + 9 * idcl;
    const int offc = 4 * pc + idcl * 36 + (c * (c - 1)) / 2;

    u16* hw = hlds[wv];

    half8 KB[6], RB[6];
#pragma unroll
    for (int t = 0; t < 6; ++t) {
        KB[t] = *(const half8*)(KPB + t * 512 + lane * 8);
        RB[t] = *(const half8*)(RPB + t * 512 + lane * 8);
    }
    float xzb[6], hzb[6];
#pragma unroll
    for (int t = 0; t < 6; ++t) { xzb[t] = bp[t * 16 + col]; hzb[t] = bp[96 + t * 16 + col]; }

    half8 Ah = *(const half8*)(ps_row(ps0, ps1, ps2, pc) + q * 8);
    float hold[2][4];
#pragma unroll
    for (int t = 0; t < 2; ++t)
#pragma unroll
        for (int r = 0; r < 4; ++r) {
            int idr = min(idx0 + q * 4 + r, cnt - 1);
            int pr = c + 9 * idr;
            hold[t][r] = h2f_u(ps_row(ps0, ps1, ps2, pr)[t * 16 + col]);
        }

    int ln = actc ? links[offc] : -1;
    half8 Ax = *(const half8*)(lnk16 + (size_t)max(ln, 0) * 32 + q * 8);

    for (int s = 0; s < L; ++s) {
        // prefetch next step's x while computing this step
        const int ln_nxt = (s + 1 < L && actc) ? links[offc + s + 1] : -1;
        const half8 Ax_nxt = *(const half8*)(lnk16 + (size_t)max(ln_nxt, 0) * 32 + q * 8);

        float4v xz[6], hz[6];
#pragma unroll
        for (int t = 0; t < 6; ++t) {
            float4v ix = {xzb[t], xzb[t], xzb[t], xzb[t]};
            float4v ih = {hzb[t], hzb[t], hzb[t], hzb[t]};
            xz[t] = __builtin_amdgcn_mfma_f32_16x16x32_f16(Ax, KB[t], ix, 0, 0, 0);
            hz[t] = __builtin_amdgcn_mfma_f32_16x16x32_f16(Ah, RB[t], ih, 0, 0, 0);
        }
#pragma unroll
        for (int t = 0; t < 2; ++t)
#pragma unroll
            for (int r = 0; r < 4; ++r) {
                const float z  = sigmoid_(xz[t][r] + hz[t][r]);
                const float rr = sigmoid_(xz[t + 2][r] + hz[t + 2][r]);
                const float hh = tanh_(xz[t + 4][r] + rr * hz[t + 4][r]);
                const float hn = z * hold[t][r] + (1.f - z) * hh;
                hold[t][r] = hn;
                hw[(q * 4 + r) * 40 + t * 16 + col] = f2h_u(hn);
            }
        // C -> A transpose via LDS
        Ah = *(const half8*)(hw + col * 40 + q * 8);
        // coalesced flush: 2 links x 32 consecutive dims per atomic instr
        const int half_ = lane >> 5, kk = lane & 31;
#pragma unroll
        for (int j2 = 0; j2 < 8; ++j2) {
            const int src = 2 * j2 + half_;
            const int tgt = __shfl(ln, src);
            const float v = h2f_u(hw[src * 40 + kk]);
            if (tgt >= 0) unsafeAtomicAdd(m_acc + (size_t)tgt * 32 + kk, v);
        }
        ln = ln_nxt; Ax = Ax_nxt;
    }
    if (actc) {
        uint4 tmp; __builtin_memcpy(&tmp, &Ah, 16);
        *(uint4*)(ps_row(ps0, ps1, ps2, pc) + q * 8) = tmp;
    }
}

// ---- fp16 MFMA link GRU: 16 links/wave, one step ---------------------------
// Zeroes m_io in-place after consuming it (each thread rewrites exactly the
// 8 floats it read -> race-free). Replaces 3 of the 4 memset dispatches.
__global__ __launch_bounds__(256) void link_gru_mfma(
    const u16* __restrict__ KLB, const u16* __restrict__ RLB,
    const float* __restrict__ bl,
    float* __restrict__ m_io, u16* __restrict__ lnk16)
{
    __shared__ u16 hlds[4][16 * 40];
    const int tid = threadIdx.x;
    const int wv = tid >> 6, lane = tid & 63;
    const int q = lane >> 4, col = lane & 15;
    const int w = blockIdx.x * 4 + wv;
    if (w >= NLINKS / 16) return;
    const int base = w * 16;
    u16* hw = hlds[wv];

    half8 KB[6], RB[6];
#pragma unroll
    for (int t = 0; t < 6; ++t) {
        KB[t] = *(const half8*)(KLB + t * 512 + lane * 8);
        RB[t] = *(const half8*)(RLB + t * 512 + lane * 8);
    }
    float xzb[6], hzb[6];
#pragma unroll
    for (int t = 0; t < 6; ++t) { xzb[t] = bl[t * 16 + col]; hzb[t] = bl[96 + t * 16 + col]; }

    // x = m row (fp32) -> fp16 A-frag;  h = link row (fp16) A-frag + C-layout copy
    half8 Ax;
    {
        float4* mr = (float4*)(m_io + (size_t)(base + col) * 32 + q * 8);
        float4 a = mr[0], b = mr[1];
        _Float16 xv[8] = {(_Float16)a.x, (_Float16)a.y, (_Float16)a.z, (_Float16)a.w,
                          (_Float16)b.x, (_Float16)b.y, (_Float16)b.z, (_Float16)b.w};
        __builtin_memcpy(&Ax, xv, 16);
        const float4 z4 = make_float4(0.f, 0.f, 0.f, 0.f);
        mr[0] = z4; mr[1] = z4;               // zero for the next iteration
    }
    half8 Ah = *(const half8*)(lnk16 + (size_t)(base + col) * 32 + q * 8);
    float hold[2][4];
#pragma unroll
    for (int t = 0; t < 2; ++t)
#pragma unroll
        for (int r = 0; r < 4; ++r)
            hold[t][r] = h2f_u(lnk16[(size_t)(base + q * 4 + r) * 32 + t * 16 + col]);

    float4v xz[6], hz[6];
#pragma unroll
    for (int t = 0; t < 6; ++t) {
        float4v ix = {xzb[t], xzb[t], xzb[t], xzb[t]};
        float4v ih = {hzb[t], hzb[t], hzb[t], hzb[t]};
        xz[t] = __builtin_amdgcn_mfma_f32_16x16x32_f16(Ax, KB[t], ix, 0, 0, 0);
        hz[t] = __builtin_amdgcn_mfma_f32_16x16x32_f16(Ah, RB[t], ih, 0, 0, 0);
    }
#pragma unroll
    for (int t = 0; t < 2; ++t)
#pragma unroll
        for (int r = 0; r < 4; ++r) {
            const float z  = sigmoid_(xz[t][r] + hz[t][r]);
            const float rr = sigmoid_(xz[t + 2][r] + hz[t + 2][r]);
            const float hh = tanh_(xz[t + 4][r] + rr * hz[t + 4][r]);
            const float hn = z * hold[t][r] + (1.f - z) * hh;
            hw[(q * 4 + r) * 40 + t * 16 + col] = f2h_u(hn);
        }
    // transpose -> contiguous fp16 row store
    {
        uint4 tmp = *(const uint4*)(hw + col * 40 + q * 8);
        *(uint4*)(lnk16 + (size_t)(base + col) * 32 + q * 8) = tmp;
    }
}

// ---- fp16 MFMA readout: 32 paths/wave, each B-frag load feeds 2 MFMAs ------
// r0/r2/r4 all pinned at ~105 us with 16 paths/wave re-streaming 147KB of
// B-frags per wave. This halves the B-frag stream AND the wave count.
__global__ __launch_bounds__(256, 2) void readout_mfma(
    u16* ps0, u16* ps1, u16* ps2,
    const u16* __restrict__ W1T, const u16* __restrict__ W2T,
    const u16* __restrict__ WFPT,
    const float* __restrict__ b1f, const float* __restrict__ b2f,
    const float* __restrict__ Wff,
    const int* __restrict__ flag, void* __restrict__ out)
{
    __shared__ u16  sA[4][4096];
    __shared__ float sB1[256], sB2[256], sWf[578];
    const int tid = threadIdx.x;
    if (tid < 256) { sB1[tid] = b1f[tid]; sB2[tid] = b2f[tid]; }
    for (int i = tid; i < 578; i += 256) sWf[i] = Wff[i];
    __syncthreads();

    const int w = tid >> 6, lane = tid & 63;
    const int col = lane & 15, q = lane >> 4;
    const int pbase = blockIdx.x * 128 + w * 32;      // 32 paths per wave (2 tiles)
    u16* sAw = sA[w];

    const half8 wfp = *(const half8*)(WFPT + lane * 8);
    const int paA = min(pbase + col, NPATHS - 1);
    const int paB = min(pbase + 16 + col, NPATHS - 1);
    const half8 apsA = *(const half8*)(ps_row(ps0, ps1, ps2, paA) + q * 8);
    const half8 apsB = *(const half8*)(ps_row(ps0, ps1, ps2, paB) + q * 8);

    // ps @ Wfp tails early (frees aps regs after W1)
    float4v accpA = {0.f, 0.f, 0.f, 0.f}, accpB = {0.f, 0.f, 0.f, 0.f};
    accpA = __builtin_amdgcn_mfma_f32_16x16x32_f16(apsA, wfp, accpA, 0, 0, 0);
    accpB = __builtin_amdgcn_mfma_f32_16x16x32_f16(apsB, wfp, accpB, 0, 0, 0);

    // ---- W1 phase, tile A: h1 -> sA -> afrA regs ----
#pragma unroll
    for (int t = 0; t < 16; ++t) {
        const half8 bfrag = *(const half8*)(W1T + t * 512 + lane * 8);
        float4v acc = {0.f, 0.f, 0.f, 0.f};
        acc = __builtin_amdgcn_mfma_f32_16x16x32_f16(apsA, bfrag, acc, 0, 0, 0);
        const int kb = t >> 1;
        const int qp = 2 * (t & 1) + (col >> 3);
#pragma unroll
        for (int rI = 0; rI < 4; ++rI) {
            const int m = q * 4 + rI;
            const float h1 = selu_(acc[rI] + sB1[t * 16 + col]);
            sAw[kb * 512 + qp * 128 + m * 8 + (col & 7)] = f2h_u(h1);
        }
    }
    half8 afrA[8];
#pragma unroll
    for (int kb = 0; kb < 8; ++kb)
        afrA[kb] = *(const half8*)(sAw + kb * 512 + lane * 8);

    // ---- W1 phase, tile B: h1 -> sA (overwrite; read per-kb in W2) ----
#pragma unroll
    for (int t = 0; t < 16; ++t) {
        const half8 bfrag = *(const half8*)(W1T + t * 512 + lane * 8);
        float4v acc = {0.f, 0.f, 0.f, 0.f};
        acc = __builtin_amdgcn_mfma_f32_16x16x32_f16(apsB, bfrag, acc, 0, 0, 0);
        const int kb = t >> 1;
        const int qp = 2 * (t & 1) + (col >> 3);
#pragma unroll
        for (int rI = 0; rI < 4; ++rI) {
            const int m = q * 4 + rI;
            const float h1 = selu_(acc[rI] + sB1[t * 16 + col]);
            sAw[kb * 512 + qp * 128 + m * 8 + (col & 7)] = f2h_u(h1);
        }
    }

    // ---- W2 phase: one B-frag load -> 2 MFMAs (tiles A and B) ----
    float4v a2A[16], a2B[16];
#pragma unroll
    for (int t = 0; t < 16; ++t) {
        a2A[t] = (float4v){0.f, 0.f, 0.f, 0.f};
        a2B[t] = (float4v){0.f, 0.f, 0.f, 0.f};
    }
#pragma unroll
    for (int kb = 0; kb < 8; ++kb) {
        const half8 afrB = *(const half8*)(sAw + kb * 512 + lane * 8);
#pragma unroll
        for (int t = 0; t < 16; ++t) {
            const half8 bfrag = *(const half8*)(W2T + (kb * 16 + t) * 512 + lane * 8);
            a2A[t] = __builtin_amdgcn_mfma_f32_16x16x32_f16(afrA[kb], bfrag, a2A[t], 0, 0, 0);
            a2B[t] = __builtin_amdgcn_mfma_f32_16x16x32_f16(afrB,     bfrag, a2B[t], 0, 0, 0);
        }
    }

    // ---- tail: h2 = selu(.+b2); pred = h2@Wf2 + ps@Wfp + bf ----
    float p0A[4] = {0.f, 0.f, 0.f, 0.f}, p1A[4] = {0.f, 0.f, 0.f, 0.f};
    float p0B[4] = {0.f, 0.f, 0.f, 0.f}, p1B[4] = {0.f, 0.f, 0.f, 0.f};
#pragma unroll
    for (int t = 0; t < 16; ++t) {
        const int n = t * 16 + col;
        const float wf0 = sWf[2 * n], wf1 = sWf[2 * n + 1];
#pragma unroll
        for (int rI = 0; rI < 4; ++rI) {
            const float h2A = selu_(a2A[t][rI] + sB2[n]);
            const float h2B = selu_(a2B[t][rI] + sB2[n]);
            p0A[rI] += h2A * wf0; p1A[rI] += h2A * wf1;
            p0B[rI] += h2B * wf0; p1B[rI] += h2B * wf1;
        }
    }
#pragma unroll
    for (int msk = 1; msk < 16; msk <<= 1) {
#pragma unroll
        for (int rI = 0; rI < 4; ++rI) {
            p0A[rI] += __shfl_xor(p0A[rI], msk);
            p1A[rI] += __shfl_xor(p1A[rI], msk);
            p0B[rI] += __shfl_xor(p0B[rI], msk);
            p1B[rI] += __shfl_xor(p1B[rI], msk);
        }
    }
    float ocA[4], ocB[4];
#pragma unroll
    for (int rI = 0; rI < 4; ++rI) {
        ocA[rI] = __shfl_xor(accpA[rI], 1);
        ocB[rI] = __shfl_xor(accpB[rI], 1);
    }
    if (col == 0) {
        const int isbf = *flag;
#pragma unroll
        for (int rI = 0; rI < 4; ++rI) {
            const int ppA = pbase + q * 4 + rI;
            const int ppB = pbase + 16 + q * 4 + rI;
            if (ppA < NPATHS) {
                const float s0 = p0A[rI] + accpA[rI] + sWf[576];
                const float s1 = p1A[rI] + ocA[rI]   + sWf[577];
                if (isbf) {
                    __hip_bfloat162 o;
                    o.x = __float2bfloat16(s0); o.y = __float2bfloat16(s1);
                    ((__hip_bfloat162*)out)[ppA] = o;
                } else ((float2*)out)[ppA] = make_float2(s0, s1);
            }
            if (ppB < NPATHS) {
                const float s0 = p0B[rI] + accpB[rI] + sWf[576];
                const float s1 = p1B[rI] + ocB[rI]   + sWf[577];
                if (isbf) {
                    __hip_bfloat162 o;
                    o.x = __float2bfloat16(s0); o.y = __float2bfloat16(s1);
                    ((__hip_bfloat162*)out)[ppB] = o;
                } else ((float2*)out)[ppB] = make_float2(s0, s1);
            }
        }
    }
}

extern "C" void kernel_launch(void* const* d_in, const int* in_sizes, int n_in,
                              void* d_out, int out_size, void* d_ws, size_t ws_size,
                              hipStream_t stream)
{
    const int* links = (const int*)d_in[2];
    float* wsf = (float*)d_ws;
    u16*   wsu = (u16*)d_ws;
    int*   flag = (int*)d_ws;

    u16* wps = (u16*)(wsf + F_PS);
    u16 *ps0, *ps1, *ps2;
    if (ws_size >= (size_t)F_PS * 4 + 6400000 + 256) {
        ps0 = wps; ps1 = wps + (size_t)49999 * 32; ps2 = wps + (size_t)99998 * 32;
    } else {
        ps0 = (u16*)d_in[3]; ps1 = (u16*)d_in[4]; ps2 = wps;  // 2 spill rows
    }

    probe_kernel<<<1, 64, 0, stream>>>((const u32*)d_in[0], flag);
    init_kernel<<<1599, 256, 0, stream>>>(d_in[1], d_in[0], flag, wsf, wsu, ps0, ps1, ps2,
                                          d_in[10], d_in[11], d_in[12],
                                          d_in[7], d_in[8], d_in[9],
                                          d_in[13], d_in[14], d_in[15], d_in[16],
                                          d_in[17], d_in[18]);
    // one memset before the loop; link_gru re-zeroes m_acc in-place thereafter
    hipMemsetAsync(wsf + F_MAC, 0, NLINKS * 32 * sizeof(float), stream);

    const int pg_blocks = 9 * ((GRP + 3) / 4);   // class-interleaved grid (1566)
    const int lg_blocks = (NLINKS / 16 + 3) / 4;
    for (int t = 0; t < TITERS; ++t) {
        path_gru_mfma<<<pg_blocks, 256, 0, stream>>>(
            links, wsu + U_KPB, wsu + U_RPB, wsf + F_BP,
            wsu + U_LNK, ps0, ps1, ps2, wsf + F_MAC);
        link_gru_mfma<<<lg_blocks, 256, 0, stream>>>(
            wsu + U_KLB, wsu + U_RLB, wsf + F_BL, wsf + F_MAC, wsu + U_LNK);
    }
    readout_mfma<<<(NPATHS + 127) / 128, 256, 0, stream>>>(
        ps0, ps1, ps2,
        wsu + U_W1T, wsu + U_W2T, wsu + U_WFP,
        wsf + F_B1, wsf + F_B2, wsf + F_WF, flag, d_out);
}